// Round 1
// baseline (3485.238 us; speedup 1.0000x reference)
//
#include <hip/hip_runtime.h>

#define N_DIM 16
#define CIN   64
#define TT    512
#define VV    22
#define COUT  256
#define PAD   24   // LDS row stride for 22-wide tiles (16B-aligned rows)
#define OPAD  23   // outs stride (odd -> conflict-free strided writes)

__global__ __launch_bounds__(256, 4) void agcn_fused(
    const float* __restrict__ x, const float* __restrict__ A,
    const float* __restrict__ Wa, const float* __restrict__ ba,
    const float* __restrict__ Wb, const float* __restrict__ bb,
    const float* __restrict__ Wd, const float* __restrict__ bd,
    float* __restrict__ out)
{
    const int t   = blockIdx.x;
    const int n   = blockIdx.y;
    const int tid = threadIdx.x;

    // Overlaid shared memory (29696 B total):
    //  [0,1536)   xs   [64][24]        (dead after phase 4)
    //  [1536,3072) A1s [64][24]        (dead after phase 2)
    //  [3072,4608) A2s [64][24]        (dead after phase 2)
    //  [4608,5136) Ss  [22][24]        (dead after phase 3)
    //  [5136,5664) Ps  [22][24]        (dead after phase 4)
    //  [0,5888)   outs [256][23]       (phase 5+, overlays the dead ones)
    //  [5888,7424) zs  [64][24]        (live phase 4 -> 5)
    __shared__ float smem[7424];
    float* xs   = smem;
    float* A1s  = smem + 1536;
    float* A2s  = smem + 3072;
    float* Ss   = smem + 4608;
    float* Ps   = smem + 5136;
    float* outs = smem;
    float* zs   = smem + 5888;

    // ---- Phase 0: stage x[n,:,t,:] (64x22) and A tile (22x22) ----
    for (int f = tid; f < CIN * VV; f += 256) {
        int c = f / VV, v = f - c * VV;
        xs[c * PAD + v] = x[(((size_t)n * CIN + c) * TT + t) * VV + v];
    }
    {
        const float* Ag = A + (((size_t)n * TT + t) * VV) * VV;
        for (int f = tid; f < VV * VV; f += 256) {
            int u = f / VV, v = f - u * VV;
            Ps[u * PAD + v] = Ag[f] + 1e-6f;   // A + PA(=1e-6), softmax added later
        }
    }
    __syncthreads();

    // ---- Phase 1: A1 = Wa@xs + ba, A2 = Wb@xs + bb  (each thread: one row pair x u-quarter)
    {
        const int r  = tid & 63;
        const int q  = tid >> 6;                 // u-quarter 0..3
        const int us = (q * VV) >> 2;            // 0,5,11,16
        const int ue = ((q + 1) * VV) >> 2;      // 5,11,16,22
        const float* War = Wa + r * CIN;
        const float* Wbr = Wb + r * CIN;
        float acc1[6], acc2[6];
        const float b1 = ba[r], b2 = bb[r];
        #pragma unroll
        for (int u = 0; u < 6; ++u) { acc1[u] = b1; acc2[u] = b2; }
        for (int c = 0; c < CIN; c += 4) {
            float4 wa4 = *reinterpret_cast<const float4*>(War + c);
            float4 wb4 = *reinterpret_cast<const float4*>(Wbr + c);
            #pragma unroll
            for (int u = 0; u < 6; ++u) {        // overcompute u=5 on 5-wide quarters
                float x0 = xs[(c + 0) * PAD + us + u];
                float x1 = xs[(c + 1) * PAD + us + u];
                float x2 = xs[(c + 2) * PAD + us + u];
                float x3 = xs[(c + 3) * PAD + us + u];
                acc1[u] += wa4.x * x0 + wa4.y * x1 + wa4.z * x2 + wa4.w * x3;
                acc2[u] += wb4.x * x0 + wb4.y * x1 + wb4.z * x2 + wb4.w * x3;
            }
        }
        #pragma unroll
        for (int u = 0; u < 6; ++u) {
            if (us + u < ue) {
                A1s[r * PAD + us + u] = acc1[u];
                A2s[r * PAD + us + u] = acc2[u];
            }
        }
    }
    __syncthreads();

    // ---- Phase 2: scores[u][v] = (1/64) * sum_i A1[i][u] * A2[i][v] ----
    for (int f = tid; f < VV * VV; f += 256) {
        int u = f / VV, v = f - u * VV;
        float s = 0.f;
        for (int i = 0; i < CIN; ++i)
            s += A1s[i * PAD + u] * A2s[i * PAD + v];
        Ss[u * PAD + v] = s * (1.0f / 64.0f);
    }
    __syncthreads();

    // ---- Phase 3: softmax over u (per column v); Ps += softmax ----
    if (tid < VV) {
        const int v = tid;
        float m = -1e30f;
        #pragma unroll
        for (int u = 0; u < VV; ++u) m = fmaxf(m, Ss[u * PAD + v]);
        float sum = 0.f;
        #pragma unroll
        for (int u = 0; u < VV; ++u) sum += __expf(Ss[u * PAD + v] - m);
        const float inv = 1.0f / sum;
        #pragma unroll
        for (int u = 0; u < VV; ++u)
            Ps[u * PAD + v] += __expf(Ss[u * PAD + v] - m) * inv;
    }
    __syncthreads();

    // ---- Phase 4: zs[c][u] = sum_w Ps[u][w] * xs[c][w] ----
    for (int f = tid; f < CIN * VV; f += 256) {
        int c = f / VV, u = f - c * VV;
        float s = 0.f;
        #pragma unroll
        for (int w = 0; w < VV; ++w)
            s += Ps[u * PAD + w] * xs[c * PAD + w];
        zs[c * PAD + u] = s;
    }
    __syncthreads();   // also fences all reads of xs/Ps before outs overlays them

    // ---- Phase 5: out[o][:] = relu(Wd[o,:] @ zs + bd[o]), o = tid ----
    {
        const int o = tid;
        const float* Wr = Wd + o * CIN;
        float acc[VV];
        const float b = bd[o];
        #pragma unroll
        for (int u = 0; u < VV; ++u) acc[u] = b;
        for (int c = 0; c < CIN; c += 4) {
            float4 w4 = *reinterpret_cast<const float4*>(Wr + c);
            #pragma unroll
            for (int cc = 0; cc < 4; ++cc) {
                const float w = (cc == 0) ? w4.x : (cc == 1) ? w4.y : (cc == 2) ? w4.z : w4.w;
                const float* zr = zs + (c + cc) * PAD;
                #pragma unroll
                for (int uq = 0; uq < 5; ++uq) {   // wave-uniform float4 LDS broadcasts
                    float4 zq = *reinterpret_cast<const float4*>(zr + uq * 4);
                    acc[uq * 4 + 0] += w * zq.x;
                    acc[uq * 4 + 1] += w * zq.y;
                    acc[uq * 4 + 2] += w * zq.z;
                    acc[uq * 4 + 3] += w * zq.w;
                }
                float2 zt = *reinterpret_cast<const float2*>(zr + 20);
                acc[20] += w * zt.x;
                acc[21] += w * zt.y;
            }
        }
        #pragma unroll
        for (int u = 0; u < VV; ++u)
            outs[o * OPAD + u] = fmaxf(acc[u], 0.f);
    }
    __syncthreads();

    // ---- Phase 6: coalesced-by-row writeback ----
    {
        const size_t obase = (size_t)n * COUT * TT * VV + (size_t)t * VV;
        for (int f = tid; f < COUT * VV; f += 256) {
            int o = f / VV, u = f - o * VV;
            out[obase + (size_t)o * (TT * VV) + u] = outs[o * OPAD + u];
        }
    }
}

extern "C" void kernel_launch(void* const* d_in, const int* in_sizes, int n_in,
                              void* d_out, int out_size, void* d_ws, size_t ws_size,
                              hipStream_t stream) {
    const float* x  = (const float*)d_in[0];
    const float* A  = (const float*)d_in[1];
    const float* Wa = (const float*)d_in[2];
    const float* ba = (const float*)d_in[3];
    const float* Wb = (const float*)d_in[4];
    const float* bb = (const float*)d_in[5];
    const float* Wd = (const float*)d_in[6];
    const float* bd = (const float*)d_in[7];
    float* outp     = (float*)d_out;

    dim3 grid(TT, N_DIM);
    agcn_fused<<<grid, 256, 0, stream>>>(x, A, Wa, ba, Wb, bb, Wd, bd, outp);
}

// Round 2
// 412.591 us; speedup vs baseline: 8.4472x; 8.4472x over previous
//
#include <hip/hip_runtime.h>

#define N_DIM 16
#define CIN   64
#define TT    512
#define VV    22
#define COUT  256
#define PAD   24    // LDS row stride for 22-wide tiles
#define OPAD  23
#define TB    8     // t-tile in kernel 2
#define ZROW  176   // TB*VV
#define ZPAD  188   // LDS row stride for Zs (16B-aligned rows, < 64KB total)
#define WPAD  68    // LDS row stride for Wt

// ============================ Kernel 1: attention + aggregate ============================
// One block per (n,t). Writes z in layout (N, T/TB, C, TB, V): contiguous 5632B per block.
__global__ __launch_bounds__(256, 6) void agcn_attn(
    const float* __restrict__ x, const float* __restrict__ A,
    const float* __restrict__ Wa, const float* __restrict__ ba,
    const float* __restrict__ Wb, const float* __restrict__ bb,
    float* __restrict__ z)
{
    const int bx = blockIdx.x;
    const int t  = (bx & 7) * 64 + (bx >> 3);   // XCD swizzle: adjacent t -> same XCD
    const int n  = blockIdx.y;
    const int tid = threadIdx.x;

    __shared__ float xs[CIN * PAD];
    __shared__ float A1s[CIN * PAD];
    __shared__ float A2s[CIN * PAD];
    __shared__ float Ss[VV * PAD];
    __shared__ float Ps[VV * PAD];

    // ---- Phase 0: stage x[n,:,t,:] (64x22) and A tile (22x22) ----
    for (int f = tid; f < CIN * VV; f += 256) {
        int c = f / VV, v = f - c * VV;
        xs[c * PAD + v] = x[(((size_t)n * CIN + c) * TT + t) * VV + v];
    }
    {
        const float* Ag = A + (((size_t)n * TT + t) * VV) * VV;
        for (int f = tid; f < VV * VV; f += 256) {
            int u = f / VV, v = f - u * VV;
            Ps[u * PAD + v] = Ag[f] + 1e-6f;
        }
    }
    __syncthreads();

    // ---- Phase 1: A1 = Wa@xs + ba, A2 = Wb@xs + bb ----
    {
        const int r  = tid & 63;
        const int q  = tid >> 6;
        const int us = (q * VV) >> 2;
        const int ue = ((q + 1) * VV) >> 2;
        const float* War = Wa + r * CIN;
        const float* Wbr = Wb + r * CIN;
        float acc1[6], acc2[6];
        const float b1 = ba[r], b2 = bb[r];
        #pragma unroll
        for (int u = 0; u < 6; ++u) { acc1[u] = b1; acc2[u] = b2; }
        for (int c = 0; c < CIN; c += 4) {
            float4 wa4 = *reinterpret_cast<const float4*>(War + c);
            float4 wb4 = *reinterpret_cast<const float4*>(Wbr + c);
            #pragma unroll
            for (int u = 0; u < 6; ++u) {
                float x0 = xs[(c + 0) * PAD + us + u];
                float x1 = xs[(c + 1) * PAD + us + u];
                float x2 = xs[(c + 2) * PAD + us + u];
                float x3 = xs[(c + 3) * PAD + us + u];
                acc1[u] += wa4.x * x0 + wa4.y * x1 + wa4.z * x2 + wa4.w * x3;
                acc2[u] += wb4.x * x0 + wb4.y * x1 + wb4.z * x2 + wb4.w * x3;
            }
        }
        #pragma unroll
        for (int u = 0; u < 6; ++u) {
            if (us + u < ue) {
                A1s[r * PAD + us + u] = acc1[u];
                A2s[r * PAD + us + u] = acc2[u];
            }
        }
    }
    __syncthreads();

    // ---- Phase 2: scores ----
    for (int f = tid; f < VV * VV; f += 256) {
        int u = f / VV, v = f - u * VV;
        float s = 0.f;
        #pragma unroll 8
        for (int i = 0; i < CIN; ++i)
            s += A1s[i * PAD + u] * A2s[i * PAD + v];
        Ss[u * PAD + v] = s * (1.0f / 64.0f);
    }
    __syncthreads();

    // ---- Phase 3: softmax over u (per column v); Ps += softmax ----
    if (tid < VV) {
        const int v = tid;
        float m = -1e30f;
        #pragma unroll
        for (int u = 0; u < VV; ++u) m = fmaxf(m, Ss[u * PAD + v]);
        float sum = 0.f;
        #pragma unroll
        for (int u = 0; u < VV; ++u) sum += __expf(Ss[u * PAD + v] - m);
        const float inv = 1.0f / sum;
        #pragma unroll
        for (int u = 0; u < VV; ++u)
            Ps[u * PAD + v] += __expf(Ss[u * PAD + v] - m) * inv;
    }
    __syncthreads();

    // ---- Phase 4: z[c][u] = sum_w Ps[u][w]*xs[c][w], store contiguous ----
    {
        const int tb  = t >> 3;
        const int ttl = t & 7;
        float* zdst = z + (((size_t)n * (TT / TB) + tb) * CIN) * ZROW + ttl * VV;
        for (int f = tid; f < CIN * VV; f += 256) {
            int c = f / VV, u = f - c * VV;
            float s = 0.f;
            #pragma unroll
            for (int w = 0; w < VV; ++w)
                s += Ps[u * PAD + w] * xs[c * PAD + w];
            zdst[c * ZROW + u] = s;
        }
    }
}

// ============================ Kernel 2: output GEMM + ReLU ============================
// Block: (tb, ob, n). M=64 o's, N=176 tv, K=64. Thread (ty,tx): 4 o x 12 tv register tile.
__global__ __launch_bounds__(256, 2) void agcn_out(
    const float* __restrict__ z, const float* __restrict__ Wd,
    const float* __restrict__ bd, float* __restrict__ out)
{
    const int tb = blockIdx.x;   // 0..63
    const int ob = blockIdx.y;   // 0..3
    const int n  = blockIdx.z;   // 0..15
    const int tid = threadIdx.x;
    const int tx = tid & 15;     // tv group: cols [tx*12, tx*12+12)
    const int ty = tid >> 4;     // o group:  rows [ty*4, ty*4+4)

    __shared__ float Zs[CIN * ZPAD];   // [k][tv] 64x188 -> 47.1KB
    __shared__ float Wt[CIN * WPAD];   // [k][o]  64x68  -> 17.4KB   (total 64512B)

    // stage Wd block transposed: Wt[k][oo] = Wd[ob*64+oo][k]
    for (int f = tid; f < 64 * CIN; f += 256) {
        int oo = f >> 6, k = f & 63;
        Wt[k * WPAD + oo] = Wd[(size_t)(ob * 64 + oo) * CIN + k];
    }
    // stage z tile (contiguous 45KB): Zs[c][r], r = ttl*22+v
    {
        const float* zsrc = z + (((size_t)n * (TT / TB) + tb) * CIN) * ZROW;
        for (int f4 = tid; f4 < (CIN * ZROW) / 4; f4 += 256) {
            float4 val = *reinterpret_cast<const float4*>(zsrc + (size_t)f4 * 4);
            int i = f4 * 4;
            int c = i / ZROW;
            int r = i - c * ZROW;        // multiple of 4, <= 172: float4 stays in row
            *reinterpret_cast<float4*>(&Zs[c * ZPAD + r]) = val;
        }
    }
    __syncthreads();

    const int o0 = ob * 64 + ty * 4;
    float acc[4][12];
    #pragma unroll
    for (int j = 0; j < 4; ++j) {
        const float b = bd[o0 + j];
        #pragma unroll
        for (int m = 0; m < 12; ++m) acc[j][m] = b;
    }

    #pragma unroll 4
    for (int k = 0; k < CIN; ++k) {
        float4 w4 = *reinterpret_cast<const float4*>(&Wt[k * WPAD + ty * 4]);
        float4 z0 = *reinterpret_cast<const float4*>(&Zs[k * ZPAD + tx * 12 + 0]);
        float4 z1 = *reinterpret_cast<const float4*>(&Zs[k * ZPAD + tx * 12 + 4]);
        float4 z2 = *reinterpret_cast<const float4*>(&Zs[k * ZPAD + tx * 12 + 8]);
        const float wv[4] = {w4.x, w4.y, w4.z, w4.w};
        const float zv[12] = {z0.x, z0.y, z0.z, z0.w, z1.x, z1.y, z1.z, z1.w,
                              z2.x, z2.y, z2.z, z2.w};
        #pragma unroll
        for (int j = 0; j < 4; ++j)
            #pragma unroll
            for (int m = 0; m < 12; ++m)
                acc[j][m] += wv[j] * zv[m];
    }

    // store: per o-row, 12 consecutive floats at tv = tx*12+m (mask tail >= 176)
    {
        const int tvb = tx * 12;
        #pragma unroll
        for (int j = 0; j < 4; ++j) {
            float* op = out + ((size_t)(n * COUT + o0 + j)) * (TT * VV) + (size_t)tb * ZROW + tvb;
            #pragma unroll
            for (int m = 0; m < 12; ++m) {
                if (tvb + m < ZROW) op[m] = fmaxf(acc[j][m], 0.f);
            }
        }
    }
}

// ============================ Fallback: verified R1 monolithic kernel ============================
__global__ __launch_bounds__(256, 4) void agcn_fused(
    const float* __restrict__ x, const float* __restrict__ A,
    const float* __restrict__ Wa, const float* __restrict__ ba,
    const float* __restrict__ Wb, const float* __restrict__ bb,
    const float* __restrict__ Wd, const float* __restrict__ bd,
    float* __restrict__ out)
{
    const int t   = blockIdx.x;
    const int n   = blockIdx.y;
    const int tid = threadIdx.x;
    __shared__ float smem[7424];
    float* xs   = smem;
    float* A1s  = smem + 1536;
    float* A2s  = smem + 3072;
    float* Ss   = smem + 4608;
    float* Ps   = smem + 5136;
    float* outs = smem;
    float* zs   = smem + 5888;

    for (int f = tid; f < CIN * VV; f += 256) {
        int c = f / VV, v = f - c * VV;
        xs[c * PAD + v] = x[(((size_t)n * CIN + c) * TT + t) * VV + v];
    }
    {
        const float* Ag = A + (((size_t)n * TT + t) * VV) * VV;
        for (int f = tid; f < VV * VV; f += 256) {
            int u = f / VV, v = f - u * VV;
            Ps[u * PAD + v] = Ag[f] + 1e-6f;
        }
    }
    __syncthreads();
    {
        const int r  = tid & 63;
        const int q  = tid >> 6;
        const int us = (q * VV) >> 2;
        const int ue = ((q + 1) * VV) >> 2;
        const float* War = Wa + r * CIN;
        const float* Wbr = Wb + r * CIN;
        float acc1[6], acc2[6];
        const float b1 = ba[r], b2 = bb[r];
        #pragma unroll
        for (int u = 0; u < 6; ++u) { acc1[u] = b1; acc2[u] = b2; }
        for (int c = 0; c < CIN; c += 4) {
            float4 wa4 = *reinterpret_cast<const float4*>(War + c);
            float4 wb4 = *reinterpret_cast<const float4*>(Wbr + c);
            #pragma unroll
            for (int u = 0; u < 6; ++u) {
                float x0 = xs[(c + 0) * PAD + us + u];
                float x1 = xs[(c + 1) * PAD + us + u];
                float x2 = xs[(c + 2) * PAD + us + u];
                float x3 = xs[(c + 3) * PAD + us + u];
                acc1[u] += wa4.x * x0 + wa4.y * x1 + wa4.z * x2 + wa4.w * x3;
                acc2[u] += wb4.x * x0 + wb4.y * x1 + wb4.z * x2 + wb4.w * x3;
            }
        }
        #pragma unroll
        for (int u = 0; u < 6; ++u) {
            if (us + u < ue) {
                A1s[r * PAD + us + u] = acc1[u];
                A2s[r * PAD + us + u] = acc2[u];
            }
        }
    }
    __syncthreads();
    for (int f = tid; f < VV * VV; f += 256) {
        int u = f / VV, v = f - u * VV;
        float s = 0.f;
        for (int i = 0; i < CIN; ++i)
            s += A1s[i * PAD + u] * A2s[i * PAD + v];
        Ss[u * PAD + v] = s * (1.0f / 64.0f);
    }
    __syncthreads();
    if (tid < VV) {
        const int v = tid;
        float m = -1e30f;
        #pragma unroll
        for (int u = 0; u < VV; ++u) m = fmaxf(m, Ss[u * PAD + v]);
        float sum = 0.f;
        #pragma unroll
        for (int u = 0; u < VV; ++u) sum += __expf(Ss[u * PAD + v] - m);
        const float inv = 1.0f / sum;
        #pragma unroll
        for (int u = 0; u < VV; ++u)
            Ps[u * PAD + v] += __expf(Ss[u * PAD + v] - m) * inv;
    }
    __syncthreads();
    for (int f = tid; f < CIN * VV; f += 256) {
        int c = f / VV, u = f - c * VV;
        float s = 0.f;
        #pragma unroll
        for (int w = 0; w < VV; ++w)
            s += Ps[u * PAD + w] * xs[c * PAD + w];
        zs[c * PAD + u] = s;
    }
    __syncthreads();
    {
        const int o = tid;
        const float* Wr = Wd + o * CIN;
        float acc[VV];
        const float b = bd[o];
        #pragma unroll
        for (int u = 0; u < VV; ++u) acc[u] = b;
        for (int c = 0; c < CIN; c += 4) {
            float4 w4 = *reinterpret_cast<const float4*>(Wr + c);
            #pragma unroll
            for (int cc = 0; cc < 4; ++cc) {
                const float w = (cc == 0) ? w4.x : (cc == 1) ? w4.y : (cc == 2) ? w4.z : w4.w;
                const float* zr = zs + (c + cc) * PAD;
                #pragma unroll
                for (int uq = 0; uq < 5; ++uq) {
                    float4 zq = *reinterpret_cast<const float4*>(zr + uq * 4);
                    acc[uq * 4 + 0] += w * zq.x;
                    acc[uq * 4 + 1] += w * zq.y;
                    acc[uq * 4 + 2] += w * zq.z;
                    acc[uq * 4 + 3] += w * zq.w;
                }
                float2 zt = *reinterpret_cast<const float2*>(zr + 20);
                acc[20] += w * zt.x;
                acc[21] += w * zt.y;
            }
        }
        #pragma unroll
        for (int u = 0; u < VV; ++u)
            outs[o * OPAD + u] = fmaxf(acc[u], 0.f);
    }
    __syncthreads();
    {
        const size_t obase = (size_t)n * COUT * TT * VV + (size_t)t * VV;
        for (int f = tid; f < COUT * VV; f += 256) {
            int o = f / VV, u = f - o * VV;
            out[obase + (size_t)o * (TT * VV) + u] = outs[o * OPAD + u];
        }
    }
}

extern "C" void kernel_launch(void* const* d_in, const int* in_sizes, int n_in,
                              void* d_out, int out_size, void* d_ws, size_t ws_size,
                              hipStream_t stream) {
    const float* x  = (const float*)d_in[0];
    const float* A  = (const float*)d_in[1];
    const float* Wa = (const float*)d_in[2];
    const float* ba = (const float*)d_in[3];
    const float* Wb = (const float*)d_in[4];
    const float* bb = (const float*)d_in[5];
    const float* Wd = (const float*)d_in[6];
    const float* bd = (const float*)d_in[7];
    float* outp     = (float*)d_out;

    const size_t z_bytes = (size_t)N_DIM * TT * CIN * VV * sizeof(float);  // 46.1 MB
    if (ws_size >= z_bytes) {
        float* zws = (float*)d_ws;
        dim3 g1(TT, N_DIM);
        agcn_attn<<<g1, 256, 0, stream>>>(x, A, Wa, ba, Wb, bb, zws);
        dim3 g2(TT / TB, COUT / 64, N_DIM);
        agcn_out<<<g2, 256, 0, stream>>>(zws, Wd, bd, outp);
    } else {
        dim3 grid(TT, N_DIM);
        agcn_fused<<<grid, 256, 0, stream>>>(x, A, Wa, ba, Wb, bb, Wd, bd, outp);
    }
}